// Round 6
// baseline (393.025 us; speedup 1.0000x reference)
//
#include <hip/hip_runtime.h>
#include <cstdint>
#include <cstddef>

// Problem dims (B, D, F, T, H) = (256, 128, 8, 128, 128)
#define Bn 256
#define Dn 128
#define Tn 128
#define Hn 128
#define Kn 1024   // D*F
#define Mn 512    // 4*H

typedef float f32x4 __attribute__((ext_vector_type(4)));
typedef _Float16 h16x2 __attribute__((ext_vector_type(2)));
typedef _Float16 h16x8 __attribute__((ext_vector_type(8)));

__device__ __forceinline__ float fast_rcp(float x) {
#if defined(__has_builtin)
#if __has_builtin(__builtin_amdgcn_rcpf)
  return __builtin_amdgcn_rcpf(x);
#else
  return 1.0f / x;
#endif
#else
  return 1.0f / x;
#endif
}
__device__ __forceinline__ float sigm(float x) { return fast_rcp(1.0f + __expf(-x)); }
__device__ __forceinline__ float tanh_fast(float x) { return 1.0f - 2.0f * fast_rcp(__expf(2.0f * x) + 1.0f); }
__device__ __forceinline__ unsigned short f16_bits(float f) {
  union { _Float16 h; unsigned short u; } cv; cv.h = (_Float16)f; return cv.u;
}

// Permuted gate-row index: j' = 4*d + gate  (orig row = gate*128 + d)
__device__ __forceinline__ int orig_row(int rowp) { return (rowp & 3) * 128 + (rowp >> 2); }

// ---------------------------------------------------------------------------
// K1: ex[b,d] = input[b,d,:,:] . w_x   (one wave per (b,d))
// softmax shift-invariance kills the h/c/b_attn term entirely.
// ---------------------------------------------------------------------------
__global__ __launch_bounds__(256) void k_ex(const float* __restrict__ input,
                                            const float* __restrict__ w_attn,
                                            float* __restrict__ ex) {
  __shared__ float wx[Kn];
  const int tid = threadIdx.x;
  ((float4*)wx)[tid] = ((const float4*)(w_attn + 2 * Hn))[tid];
  __syncthreads();
  const int w = tid >> 6, lane = tid & 63;
  const int gid = blockIdx.x * 4 + w;  // b*128 + d
  const float4* xp = (const float4*)(input + (size_t)gid * Kn);
  const float4* wx4 = (const float4*)wx;
  float acc = 0.f;
#pragma unroll
  for (int r = 0; r < 4; ++r) {
    float4 x = xp[lane + r * 64];
    float4 ww = wx4[lane + r * 64];
    acc += x.x * ww.x + x.y * ww.y + x.z * ww.z + x.w * ww.w;
  }
#pragma unroll
  for (int off = 32; off; off >>= 1) acc += __shfl_xor(acc, off);
  if (lane == 0) ex[gid] = acc;
}

// ---------------------------------------------------------------------------
// K2: prep f16 MFMA A-fragments with PERMUTED rows.
//  blocks 0..255 : W_ih -> wfr[((mtg*32+kf)*64+lane)*8+j], mtg<32, kf<32
//  blocks 256..287: W_hh -> whfr[((mtg*4+kf)*64+lane)*8+j], mtg<32, kf<4
//  frag value = W[orig_row(mtg*16+(lane&15))][kf*32+(lane>>4)*8+j]
// ---------------------------------------------------------------------------
__global__ __launch_bounds__(256) void k_prep(const float* __restrict__ W_ih,
                                              const float* __restrict__ W_hh,
                                              unsigned short* __restrict__ wfr,
                                              unsigned short* __restrict__ whfr) {
  const int bid = blockIdx.x;
  const int tid = threadIdx.x;
  if (bid < 256) {
    const int gid = bid * 256 + tid;  // 65536
    const int lane = gid & 63;
    const int kf = (gid >> 6) & 31;
    const int mtg = gid >> 11;
    const int rowp = mtg * 16 + (lane & 15);
    const float* src = W_ih + (size_t)orig_row(rowp) * Kn + kf * 32 + (lane >> 4) * 8;
    uint4 pk;
    pk.x = (uint32_t)f16_bits(src[0]) | ((uint32_t)f16_bits(src[1]) << 16);
    pk.y = (uint32_t)f16_bits(src[2]) | ((uint32_t)f16_bits(src[3]) << 16);
    pk.z = (uint32_t)f16_bits(src[4]) | ((uint32_t)f16_bits(src[5]) << 16);
    pk.w = (uint32_t)f16_bits(src[6]) | ((uint32_t)f16_bits(src[7]) << 16);
    ((uint4*)wfr)[gid] = pk;
  } else {
    const int gid = (bid - 256) * 256 + tid;  // 8192
    const int lane = gid & 63;
    const int kf = (gid >> 6) & 3;
    const int mtg = gid >> 8;
    const int rowp = mtg * 16 + (lane & 15);
    const float* src = W_hh + (size_t)orig_row(rowp) * Hn + kf * 32 + (lane >> 4) * 8;
    uint4 pk;
    pk.x = (uint32_t)f16_bits(src[0]) | ((uint32_t)f16_bits(src[1]) << 16);
    pk.y = (uint32_t)f16_bits(src[2]) | ((uint32_t)f16_bits(src[3]) << 16);
    pk.z = (uint32_t)f16_bits(src[4]) | ((uint32_t)f16_bits(src[5]) << 16);
    pk.w = (uint32_t)f16_bits(src[6]) | ((uint32_t)f16_bits(src[7]) << 16);
    ((uint4*)whfr)[gid] = pk;
  }
}

// ---------------------------------------------------------------------------
// K3: gates GEMM (f16 single pass). grid=256 (1 block per batch, 1/CU),
// 512 thr. M=512 (all gates, permuted rows), N=128 t, K=1024. Double-buffered
// LDS staging, W-frag register double-buffer, 1 barrier/kt.
// Output gx[b][t][j'] f16 (t-major) via LDS transpose bounce.
// ---------------------------------------------------------------------------
__global__ __launch_bounds__(512, 2) void k_gates(
    const float* __restrict__ input, const float* __restrict__ ex,
    const unsigned short* __restrict__ wfr, unsigned short* __restrict__ gx) {
  // union: staging dbuf 2x16KB  |  obuf 128 x 520 f16 (133120 B)
  __shared__ __align__(16) unsigned char smem[133120];
  __shared__ float a_lds[Dn];
  __shared__ float sred[16];
  unsigned short* buf0 = (unsigned short*)smem;
  unsigned short* buf1 = buf0 + 8192;
  _Float16* obuf = (_Float16*)smem;

  const int tid = threadIdx.x;
  const int b = blockIdx.x;
  const int w = tid >> 6;          // 0..7
  const int lane = tid & 63;
  const int quad = lane >> 4;
  const int l15 = lane & 15;

  // ---- in-block softmax over ex[b,:] ----
  float v = (tid < Dn) ? ex[b * Dn + tid] : -3.4e38f;
  float m = v;
#pragma unroll
  for (int off = 32; off; off >>= 1) m = fmaxf(m, __shfl_xor(m, off));
  if (lane == 0) sred[w] = m;
  __syncthreads();
  m = sred[0];
#pragma unroll
  for (int i = 1; i < 8; ++i) m = fmaxf(m, sred[i]);
  float e = (tid < Dn) ? __expf(v - m) : 0.f;
  float s = e;
#pragma unroll
  for (int off = 32; off; off >>= 1) s += __shfl_xor(s, off);
  if (lane == 0) sred[8 + w] = s;
  __syncthreads();
  s = sred[8];
#pragma unroll
  for (int i = 1; i < 8; ++i) s += sred[8 + i];
  if (tid < Dn) a_lds[tid] = e / s;

  f32x4 acc[4][8];
#pragma unroll
  for (int i = 0; i < 4; ++i)
#pragma unroll
    for (int j = 0; j < 8; ++j) { f32x4 z = {0.f, 0.f, 0.f, 0.f}; acc[i][j] = z; }

  const float* xb = input + (size_t)b * Kn * Tn;
  // staging map: thread -> t = lane + 64*ct, 2 k-rows (kbh*2 + hf)
  const int ct = (tid >> 6) & 1;
  const int stt = lane + 64 * ct;
  const int kbh = tid >> 7;  // 0..3

  // W frags (f16): wcur[mt][kf2]
  h16x8 wcur[4][2], wnxt[4][2];
#pragma unroll
  for (int mt = 0; mt < 4; ++mt)
#pragma unroll
    for (int kf = 0; kf < 2; ++kf)
      wcur[mt][kf] = *(const h16x8*)(wfr + ((((size_t)(w * 4 + mt)) * 32 + kf) * 64 + lane) * 8);

  __syncthreads();  // a_lds ready

  // ---- stage tile 0 ----
#pragma unroll
  for (int hf = 0; hf < 2; ++hf) {
    const int kb = kbh * 2 + hf;
    const float av = a_lds[kb];
    const float* colp = xb + (size_t)(kb * 8) * Tn + stt;
    float xv[8];
#pragma unroll
    for (int j = 0; j < 8; ++j) xv[j] = colp[(size_t)j * Tn];
    uint4 pk;
    pk.x = (uint32_t)f16_bits(av * xv[0]) | ((uint32_t)f16_bits(av * xv[1]) << 16);
    pk.y = (uint32_t)f16_bits(av * xv[2]) | ((uint32_t)f16_bits(av * xv[3]) << 16);
    pk.z = (uint32_t)f16_bits(av * xv[4]) | ((uint32_t)f16_bits(av * xv[5]) << 16);
    pk.w = (uint32_t)f16_bits(av * xv[6]) | ((uint32_t)f16_bits(av * xv[7]) << 16);
    *(uint4*)(buf0 + (size_t)(kb * 128 + stt) * 8) = pk;
  }
  __syncthreads();

  for (int kt = 0; kt < 16; ++kt) {
    unsigned short* cur = (kt & 1) ? buf1 : buf0;
    unsigned short* nxt = (kt & 1) ? buf0 : buf1;
    // ---- prefetch next x tile + next W frags ----
    float xv[2][8];
    if (kt < 15) {
      const int k0n = (kt + 1) * 64;
#pragma unroll
      for (int hf = 0; hf < 2; ++hf) {
        const int kb = kbh * 2 + hf;
        const float* colp = xb + (size_t)(k0n + kb * 8) * Tn + stt;
#pragma unroll
        for (int j = 0; j < 8; ++j) xv[hf][j] = colp[(size_t)j * Tn];
      }
#pragma unroll
      for (int mt = 0; mt < 4; ++mt)
#pragma unroll
        for (int kf = 0; kf < 2; ++kf)
          wnxt[mt][kf] = *(const h16x8*)(wfr + ((((size_t)(w * 4 + mt)) * 32 + (kt + 1) * 2 + kf) * 64 + lane) * 8);
    }
    // ---- MFMA on current tile ----
#pragma unroll
    for (int kf = 0; kf < 2; ++kf) {
      h16x8 bfr[8];
      const int kbr = kf * 4 + quad;
#pragma unroll
      for (int nt = 0; nt < 8; ++nt)
        bfr[nt] = *(const h16x8*)(cur + (size_t)(kbr * 128 + nt * 16 + l15) * 8);
#pragma unroll
      for (int mt = 0; mt < 4; ++mt)
#pragma unroll
        for (int nt = 0; nt < 8; ++nt)
          acc[mt][nt] = __builtin_amdgcn_mfma_f32_16x16x32_f16(wcur[mt][kf], bfr[nt], acc[mt][nt], 0, 0, 0);
    }
    // ---- convert prefetched tile into other buffer; rotate W regs ----
    if (kt < 15) {
      const int k0n = (kt + 1) * 8;
#pragma unroll
      for (int hf = 0; hf < 2; ++hf) {
        const int kb = kbh * 2 + hf;
        const float av = a_lds[k0n + kb];
        uint4 pk;
        pk.x = (uint32_t)f16_bits(av * xv[hf][0]) | ((uint32_t)f16_bits(av * xv[hf][1]) << 16);
        pk.y = (uint32_t)f16_bits(av * xv[hf][2]) | ((uint32_t)f16_bits(av * xv[hf][3]) << 16);
        pk.z = (uint32_t)f16_bits(av * xv[hf][4]) | ((uint32_t)f16_bits(av * xv[hf][5]) << 16);
        pk.w = (uint32_t)f16_bits(av * xv[hf][6]) | ((uint32_t)f16_bits(av * xv[hf][7]) << 16);
        *(uint4*)(nxt + (size_t)(kb * 128 + stt) * 8) = pk;
      }
#pragma unroll
      for (int mt = 0; mt < 4; ++mt)
#pragma unroll
        for (int kf = 0; kf < 2; ++kf) wcur[mt][kf] = wnxt[mt][kf];
    }
    __syncthreads();
  }

  // ---- epilogue: acc -> obuf[t][j'] (pitch 520) -> global gx[b][t][j'] ----
#pragma unroll
  for (int mt = 0; mt < 4; ++mt) {
    const int j0 = (w * 4 + mt) * 16 + quad * 4;
#pragma unroll
    for (int nt = 0; nt < 8; ++nt) {
      const int t = nt * 16 + l15;
      uint2 pk;
      pk.x = (uint32_t)f16_bits(acc[mt][nt][0]) | ((uint32_t)f16_bits(acc[mt][nt][1]) << 16);
      pk.y = (uint32_t)f16_bits(acc[mt][nt][2]) | ((uint32_t)f16_bits(acc[mt][nt][3]) << 16);
      *(uint2*)(obuf + (size_t)t * 520 + j0) = pk;
    }
  }
  __syncthreads();
  {
    const int tr = tid >> 2, seg = tid & 3;
    const uint4* ls = (const uint4*)(obuf + (size_t)tr * 520 + seg * 128);
    uint4* gd = (uint4*)(gx + ((size_t)b * Tn + tr) * Mn + seg * 128);
#pragma unroll
    for (int i = 0; i < 16; ++i) gd[i] = ls[i];
  }
}

// ---------------------------------------------------------------------------
// K4: LSTM recurrence via MFMA. grid=16, 512 thr, 16 batches per block.
// Permuted rows => C-frag f32x4 of lane (quad,l15) = (i,f,g,o) for
// (d = mtg*4+quad, batch = l15): activation fully in-lane, c-state in regs.
// h redistributed via 4KB LDS B-frag buffer; gx read per-lane from global
// (prefetched 1 step ahead); out bounced through 8.25KB f32 LDS tile.
// ---------------------------------------------------------------------------
__global__ __launch_bounds__(512) void k_rec(
    const unsigned short* __restrict__ gx, const unsigned short* __restrict__ whfr,
    const float* __restrict__ b_ih, const float* __restrict__ b_hh,
    float* __restrict__ out) {
  __shared__ __align__(16) _Float16 hbuf[2048];   // [kb=16][n=16] chunks of 8
  __shared__ __align__(16) float hf32[16 * 132];  // [b][d], pitch 132

  const int tid = threadIdx.x;
  const int g = blockIdx.x;
  const int w = tid >> 6;
  const int lane = tid & 63;
  const int quad = lane >> 4;
  const int l15 = lane & 15;

  // W_hh A-frags (f16): whf[mt][kf]
  h16x8 whf[4][4];
#pragma unroll
  for (int mt = 0; mt < 4; ++mt)
#pragma unroll
    for (int kf = 0; kf < 4; ++kf)
      whf[mt][kf] = *(const h16x8*)(whfr + ((((size_t)(w * 4 + mt)) * 4 + kf) * 64 + lane) * 8);

  // bias in C-layout: bsum[mt][r] for row' = (w*4+mt)*16 + quad*4 + r
  f32x4 bsum[4];
#pragma unroll
  for (int mt = 0; mt < 4; ++mt) {
    const int drow = (w * 4 + mt) * 4 + quad;
#pragma unroll
    for (int r = 0; r < 4; ++r) {
      const int orow = r * 128 + drow;   // gate r of unit drow
      bsum[mt][r] = b_ih[orow] + b_hh[orow];
    }
  }
  float cst[4] = {0.f, 0.f, 0.f, 0.f};

  // zero hbuf (h0 = 0)
  ((uint32_t*)hbuf)[tid] = 0u;
  ((uint32_t*)hbuf)[tid + 512] = 0u;

  // per-lane gx base + j0 per mt; prefetch t=0
  const unsigned short* gxb = gx + (size_t)(g * 16 + l15) * Tn * Mn;
  int j0[4];
  uint2 gpre[4];
#pragma unroll
  for (int mt = 0; mt < 4; ++mt) {
    j0[mt] = (w * 4 + mt) * 16 + quad * 4;
    gpre[mt] = *(const uint2*)(gxb + j0[mt]);
  }
  __syncthreads();

  float* outg = out + (size_t)g * 16 * Tn * Hn;
  for (int t = 0; t < Tn; ++t) {
    // ---- read phase ----
    h16x8 bfr[4];
#pragma unroll
    for (int kf = 0; kf < 4; ++kf)
      bfr[kf] = *(const h16x8*)(hbuf + ((size_t)(kf * 4 + quad) * 16 + l15) * 8);
    if (t > 0) {
      const int bb = tid >> 5, d4 = (tid & 31) * 4;
      float4 hv = *(const float4*)(hf32 + bb * 132 + d4);
      *(float4*)(outg + ((size_t)bb * Tn + (t - 1)) * Hn + d4) = hv;
    }
    uint2 gcur[4];
#pragma unroll
    for (int mt = 0; mt < 4; ++mt) gcur[mt] = gpre[mt];
    if (t < Tn - 1) {
#pragma unroll
      for (int mt = 0; mt < 4; ++mt)
        gpre[mt] = *(const uint2*)(gxb + (size_t)(t + 1) * Mn + j0[mt]);
    }
    __syncthreads();  // reads done; writes below are safe

    // ---- acc init + MFMA ----
    f32x4 acc[4];
#pragma unroll
    for (int mt = 0; mt < 4; ++mt) {
      union { uint2 u; _Float16 h[4]; } cv; cv.u = gcur[mt];
      f32x4 a;
      a[0] = bsum[mt][0] + (float)cv.h[0];
      a[1] = bsum[mt][1] + (float)cv.h[1];
      a[2] = bsum[mt][2] + (float)cv.h[2];
      a[3] = bsum[mt][3] + (float)cv.h[3];
      acc[mt] = a;
    }
#pragma unroll
    for (int kf = 0; kf < 4; ++kf)
#pragma unroll
      for (int mt = 0; mt < 4; ++mt)
        acc[mt] = __builtin_amdgcn_mfma_f32_16x16x32_f16(whf[mt][kf], bfr[kf], acc[mt], 0, 0, 0);

    // ---- in-lane activation + state update ----
#pragma unroll
    for (int mt = 0; mt < 4; ++mt) {
      const float gi = acc[mt][0], gf = acc[mt][1], gg = acc[mt][2], go = acc[mt][3];
      const float c = sigm(gf) * cst[mt] + sigm(gi) * tanh_fast(gg);
      cst[mt] = c;
      const float h = sigm(go) * tanh_fast(c);
      const int drow = (w * 4 + mt) * 4 + quad;
      hbuf[((size_t)(drow >> 3) * 16 + l15) * 8 + (drow & 7)] = (_Float16)h;
      hf32[l15 * 132 + drow] = h;
    }
    __syncthreads();  // writes visible for next step's reads
  }
  // final output row t=127
  {
    const int bb = tid >> 5, d4 = (tid & 31) * 4;
    float4 hv = *(const float4*)(hf32 + bb * 132 + d4);
    *(float4*)(outg + ((size_t)bb * Tn + (Tn - 1)) * Hn + d4) = hv;
  }
}

// ---------------------------------------------------------------------------
extern "C" void kernel_launch(void* const* d_in, const int* in_sizes, int n_in,
                              void* d_out, int out_size, void* d_ws, size_t ws_size,
                              hipStream_t stream) {
  (void)in_sizes; (void)n_in; (void)out_size; (void)ws_size;
  const float* input = (const float*)d_in[0];
  const float* w_attn = (const float*)d_in[1];
  // d_in[2] = b_attn: dead (softmax shift-invariance), as are w_h, w_c.
  const float* W_ih = (const float*)d_in[3];
  const float* W_hh = (const float*)d_in[4];
  const float* b_ih = (const float*)d_in[5];
  const float* b_hh = (const float*)d_in[6];
  float* out = (float*)d_out;

  char* ws = (char*)d_ws;
  float* ex = (float*)ws;                                   // 131072 B
  unsigned short* wfr = (unsigned short*)(ws + 131072);      // 1 MB (W_ih f16 frags)
  unsigned short* whfr = (unsigned short*)(ws + 1179648);    // 128 KB (W_hh f16 frags)
  unsigned short* gxw = (unsigned short*)(ws + 1310720);     // 32 MB gx[b][t][j']

  k_ex<<<8192, 256, 0, stream>>>(input, w_attn, ex);
  k_prep<<<288, 256, 0, stream>>>(W_ih, W_hh, wfr, whfr);
  k_gates<<<256, 512, 0, stream>>>(input, ex, wfr, gxw);
  k_rec<<<16, 512, 0, stream>>>(gxw, whfr, b_ih, b_hh, out);
}